// Round 9
// baseline (747.488 us; speedup 1.0000x reference)
//
#include <hip/hip_runtime.h>

#define B 4
#define C 512
#define HW 4096
#define NG 32
#define GSZ 65536   // (C/NG)*HW = 16*4096

typedef unsigned short u16;
typedef unsigned int u32;
typedef __attribute__((ext_vector_type(8))) short short8;
typedef __attribute__((ext_vector_type(4))) float f32x4;

__device__ __forceinline__ float bf2f(u16 u) {
    union { u32 i; float f; } x; x.i = ((u32)u) << 16; return x.f;
}
__device__ __forceinline__ u16 f2bf(float f) {
    union { u32 i; float f; } x; x.f = f;
    u32 r = x.i + 0x7FFF + ((x.i >> 16) & 1);   // round-nearest-even
    return (u16)(r >> 16);
}

// async global->LDS, 16B per lane. LDS dest = wave-uniform base + lane*16.
__device__ __forceinline__ void gld16(const u16* g, u16* l) {
    __builtin_amdgcn_global_load_lds(
        (const __attribute__((address_space(1))) void*)g,
        (__attribute__((address_space(3))) void*)l, 16, 0, 0);
}

// ---------------- Kernel 0: fp32 -> bf16 weight conversion ----------------
__global__ __launch_bounds__(256) void conv_kernel(
        const float* __restrict__ wq, const float* __restrict__ wk,
        const float* __restrict__ wv, const float* __restrict__ wo,
        u16* __restrict__ dst) {
    const int mat = blockIdx.y;
    const float* src = (mat == 0) ? wq : (mat == 1) ? wk : (mat == 2) ? wv : wo;
    const int idx = (blockIdx.x * 256 + threadIdx.x) * 4;
    float4 v = *(const float4*)(src + idx);
    ushort4 r;
    r.x = f2bf(v.x); r.y = f2bf(v.y); r.z = f2bf(v.z); r.w = f2bf(v.w);
    *(ushort4*)(dst + (size_t)mat * (C * C) + idx) = r;
}

// ---------------- Kernel 1: GroupNorm -> bf16 xnT (b, hw, c) ----------------
__global__ __launch_bounds__(256) void gn_kernel(
        const float* __restrict__ x, const float* __restrict__ gamma,
        const float* __restrict__ beta, u16* __restrict__ xnT) {
    const int gl = blockIdx.x;                // b*32 + g
    const int b = gl >> 5, g = gl & 31;
    const size_t base = (size_t)gl * GSZ;
    const int tid = threadIdx.x;
    float s = 0.f, s2 = 0.f;
    for (int i = tid * 4; i < GSZ; i += 1024) {
        float4 v4 = *(const float4*)(x + base + i);
        s  += v4.x + v4.y + v4.z + v4.w;
        s2 += v4.x*v4.x + v4.y*v4.y + v4.z*v4.z + v4.w*v4.w;
    }
    #pragma unroll
    for (int off = 32; off > 0; off >>= 1) {
        s  += __shfl_down(s, off, 64);
        s2 += __shfl_down(s2, off, 64);
    }
    __shared__ float rs[4], rs2[4], bc[2];
    int lane = tid & 63, wid = tid >> 6;
    if (lane == 0) { rs[wid] = s; rs2[wid] = s2; }
    __syncthreads();
    if (tid == 0) {
        float ts  = rs[0] + rs[1] + rs[2] + rs[3];
        float ts2 = rs2[0] + rs2[1] + rs2[2] + rs2[3];
        float mean = ts * (1.f / GSZ);
        float var  = ts2 * (1.f / GSZ) - mean * mean;
        bc[0] = mean; bc[1] = rsqrtf(var + 1e-6f);
    }
    __syncthreads();
    const float mean = bc[0], rstd = bc[1];
    const int c0 = g * 16;
    float gm[16], bt[16];
    #pragma unroll
    for (int c = 0; c < 16; c++) {
        float gg = gamma[c0 + c] * rstd;
        gm[c] = gg;
        bt[c] = beta[c0 + c] - mean * gg;
    }
    for (int i = tid; i < HW; i += 256) {
        u32 pk[8];
        #pragma unroll
        for (int c = 0; c < 16; c += 2) {
            float a0 = x[base + (size_t)c * HW + i] * gm[c] + bt[c];
            float a1 = x[base + (size_t)(c + 1) * HW + i] * gm[c + 1] + bt[c + 1];
            pk[c >> 1] = (u32)f2bf(a0) | ((u32)f2bf(a1) << 16);
        }
        u16* dst = xnT + ((size_t)b * HW + i) * C + c0;
        *(uint4*)dst       = make_uint4(pk[0], pk[1], pk[2], pk[3]);
        *(uint4*)(dst + 8) = make_uint4(pk[4], pk[5], pk[6], pk[7]);
    }
}

// ---------------- Kernel 2: MFMA QKV projection ----------------
// A = xnT (m=i, k=c contig), B = W (n=o, k=c contig) -> D[i,o]
// q/k: store qT/kT (b,hw,c);  v: store vimg swizzled chunks (ushort4 runs)
__global__ __launch_bounds__(256) void qkv_kernel(
        const u16* __restrict__ xnT, const u16* __restrict__ wb,
        const float* __restrict__ bq, const float* __restrict__ bk,
        const float* __restrict__ bv,
        u16* __restrict__ qT, u16* __restrict__ kT, u16* __restrict__ vimg) {
    const int mat = blockIdx.y >> 2;
    const int oT0 = (blockIdx.y & 3) * 128;
    const int iT0 = blockIdx.x * 128;
    const int b = blockIdx.z;
    const u16* Ag = xnT + ((size_t)b * HW + iT0) * C;
    const u16* Bg = wb + (size_t)mat * C * C + (size_t)oT0 * C;
    const float* bias = (mat == 0) ? bq : (mat == 1) ? bk : bv;

    const int tid = threadIdx.x;
    const int w = tid >> 6, lane = tid & 63;
    const int qd = lane >> 4, nn = lane & 15;
    const int wm = w & 1, wn = w >> 1;

    __shared__ __align__(16) u16 As[2][128 * 32];
    __shared__ __align__(16) u16 Bs[2][128 * 32];

    f32x4 acc[4][4];
    #pragma unroll
    for (int mt = 0; mt < 4; mt++)
        #pragma unroll
        for (int nt = 0; nt < 4; nt++) acc[mt][nt] = (f32x4){0.f, 0.f, 0.f, 0.f};

    auto stage = [&](u16* dst, const u16* g, int c0) {
        #pragma unroll
        for (int p = 0; p < 2; p++) {
            int rbase = 32 * w + 16 * p;
            int row = rbase + (lane >> 2);
            gld16(g + (size_t)row * C + c0 + (((lane & 3) ^ ((row >> 1) & 3)) << 3),
                  dst + rbase * 32);
        }
    };

    stage(As[0], Ag, 0);
    stage(Bs[0], Bg, 0);

    for (int kt = 0; kt < 16; kt++) {
        const int cur = kt & 1;
        __syncthreads();
        if (kt < 15) {
            stage(As[cur ^ 1], Ag, (kt + 1) * 32);
            stage(Bs[cur ^ 1], Bg, (kt + 1) * 32);
        }
        short8 af[4], bf[4];
        #pragma unroll
        for (int mt = 0; mt < 4; mt++) {
            int row = 64 * wm + 16 * mt + nn;
            af[mt] = *(const short8*)&As[cur][row * 32 + ((qd ^ ((row >> 1) & 3)) << 3)];
        }
        #pragma unroll
        for (int nt = 0; nt < 4; nt++) {
            int row = 64 * wn + 16 * nt + nn;
            bf[nt] = *(const short8*)&Bs[cur][row * 32 + ((qd ^ ((row >> 1) & 3)) << 3)];
        }
        #pragma unroll
        for (int mt = 0; mt < 4; mt++)
            #pragma unroll
            for (int nt = 0; nt < 4; nt++)
                acc[mt][nt] = __builtin_amdgcn_mfma_f32_16x16x32_bf16(af[mt], bf[nt], acc[mt][nt], 0, 0, 0);
    }

    if (mat < 2) {
        u16* dstT = ((mat == 0) ? qT : kT) + (size_t)b * HW * C;
        #pragma unroll
        for (int nt = 0; nt < 4; nt++) {
            int o = oT0 + 64 * wn + 16 * nt + nn;
            float bb = bias[o];
            #pragma unroll
            for (int mt = 0; mt < 4; mt++) {
                int ib = iT0 + 64 * wm + 16 * mt + qd * 4;
                u16* p = dstT + (size_t)ib * C + o;
                p[0]     = f2bf(acc[mt][nt][0] + bb);
                p[C]     = f2bf(acc[mt][nt][1] + bb);
                p[2 * C] = f2bf(acc[mt][nt][2] + bb);
                p[3 * C] = f2bf(acc[mt][nt][3] + bb);
            }
        }
    } else {
        u16* vb = vimg + (size_t)b * 128 * 16384;
        #pragma unroll
        for (int nt = 0; nt < 4; nt++) {
            int c = oT0 + 64 * wn + 16 * nt + nn;
            float bb = bias[c];
            #pragma unroll
            for (int mt = 0; mt < 4; mt++) {
                int ib = iT0 + 64 * wm + 16 * mt + qd * 4;
                int ch = ib >> 5;
                int j0 = ib & 31;
                ushort4 st;
                st.x = f2bf(acc[mt][nt][0] + bb);
                st.y = f2bf(acc[mt][nt][1] + bb);
                st.z = f2bf(acc[mt][nt][2] + bb);
                st.w = f2bf(acc[mt][nt][3] + bb);
                *(ushort4*)&vb[(size_t)ch * 16384 + c * 32 +
                               (((j0 >> 3) ^ ((c >> 2) & 3)) << 3) + (j0 & 7)] = st;
            }
        }
    }
}

// ---------------- Kernel 3: MFMA flash attention (32-row tiles, 64-j chunks) ----------------
// Block: 32 q-rows, 4 waves, 256 thr. blockIdx.z = j-half (2048 j each).
// Chunk = 64 j (32 iterations): halves barrier-drain count vs 32-j chunks.
// Wave w = (rw = w&1 row-half) x (jh = w>>1 32-j half of the chunk); each wave
// computes two 16x16 S tiles (jt=0,1). PV: wave w owns cols [128w,128w+128),
// two k-steps (kh) of 16 MFMAs. V frags for both kh loaded at loop top from
// global vimg (coalesced, L2-resident). K single-buffered 64KB, staged after B2.
__global__ __launch_bounds__(256, 2) void attn_kernel(
        const u16* __restrict__ qT, const u16* __restrict__ kT,
        const u16* __restrict__ vimg, u16* __restrict__ Opart,
        float2* __restrict__ mlpart) {
    const int b = blockIdx.y;
    const int i0 = blockIdx.x * 32;
    const int h = blockIdx.z;          // j-half of HW
    const int tid = threadIdx.x;
    const int w = tid >> 6;
    const int lane = tid & 63;
    const int q = lane >> 4;
    const int n = lane & 15;
    const int rw = w & 1;              // S row-half
    const int jh = w >> 1;             // S 32-j half within the 64-j chunk

    __shared__ __align__(16) u16 kbuf[64 * 512];   // 64 KB, XOR-chunk swizzle
    __shared__ __align__(16) u16 pbuf[32 * 80];    // 5 KB (stride 80: conflict-free)
    __shared__ __align__(16) float mflag[4];
    __shared__ __align__(16) float lpart[2][32];

    // persistent Q A-fragments: rows i0 + rw*16 + n, k = kk*32 + q*8 .. +7
    short8 qf[16];
    {
        const u16* qrow = qT + ((size_t)b * HW + i0 + rw * 16 + n) * C + q * 8;
        #pragma unroll
        for (int k = 0; k < 16; k++) {
            uint4 u = *(const uint4*)(qrow + k * 32);
            qf[k] = *(const short8*)&u;
        }
    }
    f32x4 oacc[2][8];
    #pragma unroll
    for (int mt = 0; mt < 2; mt++)
        #pragma unroll
        for (int nt = 0; nt < 8; nt++)
            oacc[mt][nt] = (f32x4){0.f, 0.f, 0.f, 0.f};
    float mreg = 0.f;                  // block-uniform running max (lockstep)
    float lsum[4] = {0.f, 0.f, 0.f, 0.f};

    const u16* kTb = kT + (size_t)b * HW * C;
    const u16* vTb = vimg + (size_t)b * 128 * 16384;

    // K rows j (0..63): phys 16B-chunk l holds logical chunk (l ^ (j&7))
    auto stageK = [&](int gc) {   // gc in 64-j units
        const u16* gk = kTb + (size_t)gc * 64 * C;
        #pragma unroll
        for (int ii = 0; ii < 16; ii++) {
            int j = w * 16 + ii;
            gld16(gk + (size_t)j * C + ((lane ^ (j & 7)) << 3), &kbuf[j * 512]);
        }
    };

    const int gc0 = h * 32;
    stageK(gc0);
    const float scale = 0.04419417382415922f;   // 512^-0.5
    __syncthreads();   // chunk 0 staged

    #pragma unroll 1
    for (int t = 0; t < 32; ++t) {
        // ---- V fragments for both 32-j halves of chunk t (global, coalesced) ----
        uint4 vpf[2][8];
        {
            const u16* gv = vTb + (size_t)(gc0 + t) * 32768;
            #pragma unroll
            for (int kh = 0; kh < 2; kh++) {
                const u16* gvk = gv + kh * 16384;
                #pragma unroll
                for (int nt = 0; nt < 8; nt++) {
                    int c = w * 128 + nt * 16 + n;
                    vpf[kh][nt] = *(const uint4*)&gvk[c * 32 + ((q ^ ((c >> 2) & 3)) << 3)];
                }
            }
        }
        // ---- S: two 16x16 tiles (jt), each a split 2-chain of 8 MFMAs ----
        float sv[2][4];
        #pragma unroll
        for (int jt = 0; jt < 2; jt++) {
            f32x4 sa = {0.f, 0.f, 0.f, 0.f}, sb = {0.f, 0.f, 0.f, 0.f};
            const int sw = n & 7;
            const u16* kb = kbuf + (jh * 32 + jt * 16 + n) * 512;
            #pragma unroll
            for (int kk = 0; kk < 8; kk++) {
                short8 bfa = *(const short8*)&kb[(((2 * kk) * 4 + q) ^ sw) << 3];
                short8 bfb = *(const short8*)&kb[(((2 * kk + 1) * 4 + q) ^ sw) << 3];
                sa = __builtin_amdgcn_mfma_f32_16x16x32_bf16(qf[2 * kk], bfa, sa, 0, 0, 0);
                sb = __builtin_amdgcn_mfma_f32_16x16x32_bf16(qf[2 * kk + 1], bfb, sb, 0, 0, 0);
            }
            #pragma unroll
            for (int r = 0; r < 4; r++) sv[jt][r] = (sa[r] + sb[r]) * scale;
        }
        // ---- p = exp(s - mreg); exceedance flag (rare path does the reduce) ----
        float pm = fmaxf(fmaxf(fmaxf(sv[0][0], sv[0][1]), fmaxf(sv[0][2], sv[0][3])),
                         fmaxf(fmaxf(sv[1][0], sv[1][1]), fmaxf(sv[1][2], sv[1][3])));
        float flagv = -1e30f;
        if (__any(pm > mreg + 1.0f)) {
            float mx = pm;
            mx = fmaxf(mx, __shfl_xor(mx, 1));
            mx = fmaxf(mx, __shfl_xor(mx, 2));
            mx = fmaxf(mx, __shfl_xor(mx, 4));
            mx = fmaxf(mx, __shfl_xor(mx, 8));
            mx = fmaxf(mx, __shfl_xor(mx, 16));
            mx = fmaxf(mx, __shfl_xor(mx, 32));
            flagv = mx;
        }
        if (lane == 0) mflag[w] = flagv;
        #pragma unroll
        for (int jt = 0; jt < 2; jt++)
            #pragma unroll
            for (int r = 0; r < 4; r++) {
                float p = __expf(sv[jt][r] - mreg);
                lsum[r] += p;
                pbuf[(rw * 16 + q * 4 + r) * 80 + jh * 32 + jt * 16 + n] = f2bf(p);
            }
        __syncthreads();   // B2: pbuf/flags visible; kbuf reads done; vpf landed
        if (t < 31) stageK(gc0 + t + 1);   // overlaps PV; drained at B3
        f32x4 fl = *(const f32x4*)mflag;   // broadcast read
        float mnew = fmaxf(fmaxf(mreg, fl[0]), fmaxf(fmaxf(fl[1], fl[2]), fl[3]));
        // ---- O += P V  (wave w: cols 128w..128w+127, all 32 rows; 2 k-steps) ----
        #pragma unroll
        for (int kh = 0; kh < 2; kh++) {
            short8 pf[2];
            #pragma unroll
            for (int mt = 0; mt < 2; mt++)
                pf[mt] = *(const short8*)&pbuf[(mt * 16 + n) * 80 + kh * 32 + q * 8];
            #pragma unroll
            for (int nt = 0; nt < 8; nt++) {
                short8 vf = *(const short8*)&vpf[kh][nt];
                #pragma unroll
                for (int mt = 0; mt < 2; mt++)
                    oacc[mt][nt] = __builtin_amdgcn_mfma_f32_16x16x32_bf16(pf[mt], vf, oacc[mt][nt], 0, 0, 0);
            }
        }
        // ---- rare deferred rescale (exact: this chunk added at old scale) ----
        if (mnew > mreg) {
            float al = __expf(mreg - mnew);
            #pragma unroll
            for (int mt = 0; mt < 2; mt++)
                #pragma unroll
                for (int nt = 0; nt < 8; nt++) {
                    oacc[mt][nt][0] *= al; oacc[mt][nt][1] *= al;
                    oacc[mt][nt][2] *= al; oacc[mt][nt][3] *= al;
                }
            #pragma unroll
            for (int r = 0; r < 4; r++) lsum[r] *= al;
            mreg = mnew;
        }
        __syncthreads();   // B3: pbuf consumed; staged K drained
    }
    // ---- epilogue: per-(row,jh) partial l -> LDS; merge; write partials ----
    #pragma unroll
    for (int r = 0; r < 4; r++) {
        float l = lsum[r];
        l += __shfl_xor(l, 1);
        l += __shfl_xor(l, 2);
        l += __shfl_xor(l, 4);
        l += __shfl_xor(l, 8);
        if (n == 0) lpart[jh][rw * 16 + q * 4 + r] = l;
    }
    __syncthreads();
    if (jh == 0 && n == 0) {
        #pragma unroll
        for (int r = 0; r < 4; r++) {
            int row = rw * 16 + q * 4 + r;
            float2 e; e.x = mreg; e.y = lpart[0][row] + lpart[1][row];
            mlpart[((size_t)h * B + b) * HW + i0 + row] = e;
        }
    }
    #pragma unroll
    for (int mt = 0; mt < 2; mt++) {
        float inv[4];
        #pragma unroll
        for (int r = 0; r < 4; r++) {
            int row = mt * 16 + q * 4 + r;
            inv[r] = 1.f / (lpart[0][row] + lpart[1][row]);
        }
        #pragma unroll
        for (int nt = 0; nt < 8; nt++) {
            int cc = w * 128 + nt * 16 + n;
            size_t base = (((size_t)h * B + b) * HW + i0 + mt * 16 + q * 4) * C + cc;
            Opart[base        ] = f2bf(oacc[mt][nt][0] * inv[0]);
            Opart[base +   C  ] = f2bf(oacc[mt][nt][1] * inv[1]);
            Opart[base + 2 * C] = f2bf(oacc[mt][nt][2] * inv[2]);
            Opart[base + 3 * C] = f2bf(oacc[mt][nt][3] * inv[3]);
        }
    }
}

// ---------------- Kernel 3b: merge the two j-half partials ----------------
__global__ __launch_bounds__(256) void merge_kernel(
        const u16* __restrict__ Opart, const float2* __restrict__ mlpart,
        u16* __restrict__ oT) {
    const int row = blockIdx.x * 4 + (threadIdx.x >> 6);   // b*HW + i
    const int lane = threadIdx.x & 63;
    float2 e0 = mlpart[row];
    float2 e1 = mlpart[(size_t)B * HW + row];
    float m = fmaxf(e0.x, e1.x);
    float a0 = __expf(e0.x - m) * e0.y;
    float a1 = __expf(e1.x - m) * e1.y;
    float inv = 1.f / (a0 + a1);
    a0 *= inv; a1 *= inv;
    size_t off = (size_t)row * C + lane * 8;
    uint4 u0 = *(const uint4*)(Opart + off);
    uint4 u1 = *(const uint4*)(Opart + (size_t)B * HW * C + off);
    const u32* p0 = (const u32*)&u0;
    const u32* p1 = (const u32*)&u1;
    u32 s[4];
    #pragma unroll
    for (int k = 0; k < 4; k++) {
        u16 lo = f2bf(a0 * bf2f((u16)p0[k]) + a1 * bf2f((u16)p1[k]));
        u16 hi = f2bf(a0 * bf2f((u16)(p0[k] >> 16)) + a1 * bf2f((u16)(p1[k] >> 16)));
        s[k] = (u32)lo | ((u32)hi << 16);
    }
    *(uint4*)(oT + off) = make_uint4(s[0], s[1], s[2], s[3]);
}

// ---------------- Kernel 4: MFMA output projection + bias + residual ----------------
// A = wo (m=o, k=c), B = oT (n=i, k=c) -> D[o,i] (c-major output)
__global__ __launch_bounds__(256) void proj_kernel(
        const u16* __restrict__ oT, const u16* __restrict__ wob,
        const float* __restrict__ bo, const float* __restrict__ x,
        float* __restrict__ out) {
    const int o0 = blockIdx.y * 128;
    const int i0t = blockIdx.x * 128;
    const int b = blockIdx.z;
    const u16* Ag = wob + (size_t)o0 * C;
    const u16* Bg = oT + ((size_t)b * HW + i0t) * C;

    const int tid = threadIdx.x;
    const int w = tid >> 6, lane = tid & 63;
    const int qd = lane >> 4, nn = lane & 15;
    const int wm = w & 1, wn = w >> 1;

    __shared__ __align__(16) u16 As[2][128 * 32];
    __shared__ __align__(16) u16 Bs[2][128 * 32];

    f32x4 acc[4][4];
    #pragma unroll
    for (int mt = 0; mt < 4; mt++)
        #pragma unroll
        for (int nt = 0; nt < 4; nt++) acc[mt][nt] = (f32x4){0.f, 0.f, 0.f, 0.f};

    auto stage = [&](u16* dst, const u16* g, int c0) {
        #pragma unroll
        for (int p = 0; p < 2; p++) {
            int rbase = 32 * w + 16 * p;
            int row = rbase + (lane >> 2);
            gld16(g + (size_t)row * C + c0 + (((lane & 3) ^ ((row >> 1) & 3)) << 3),
                  dst + rbase * 32);
        }
    };

    stage(As[0], Ag, 0);
    stage(Bs[0], Bg, 0);

    for (int kt = 0; kt < 16; kt++) {
        const int cur = kt & 1;
        __syncthreads();
        if (kt < 15) {
            stage(As[cur ^ 1], Ag, (kt + 1) * 32);
            stage(Bs[cur ^ 1], Bg, (kt + 1) * 32);
        }
        short8 af[4], bf[4];
        #pragma unroll
        for (int mt = 0; mt < 4; mt++) {
            int row = 64 * wm + 16 * mt + nn;
            af[mt] = *(const short8*)&As[cur][row * 32 + ((qd ^ ((row >> 1) & 3)) << 3)];
        }
        #pragma unroll
        for (int nt = 0; nt < 4; nt++) {
            int row = 64 * wn + 16 * nt + nn;
            bf[nt] = *(const short8*)&Bs[cur][row * 32 + ((qd ^ ((row >> 1) & 3)) << 3)];
        }
        #pragma unroll
        for (int mt = 0; mt < 4; mt++)
            #pragma unroll
            for (int nt = 0; nt < 4; nt++)
                acc[mt][nt] = __builtin_amdgcn_mfma_f32_16x16x32_bf16(af[mt], bf[nt], acc[mt][nt], 0, 0, 0);
    }

    #pragma unroll
    for (int mt = 0; mt < 4; mt++) {
        #pragma unroll
        for (int r = 0; r < 4; r++) {
            int o = o0 + 64 * wm + 16 * mt + qd * 4 + r;
            float bb = bo[o];
            #pragma unroll
            for (int nt = 0; nt < 4; nt++) {
                int i = i0t + 64 * wn + 16 * nt + nn;
                size_t idx = ((size_t)b * C + o) * HW + i;
                out[idx] = acc[mt][nt][r] + bb + x[idx];
            }
        }
    }
}

extern "C" void kernel_launch(void* const* d_in, const int* in_sizes, int n_in,
                              void* d_out, int out_size, void* d_ws, size_t ws_size,
                              hipStream_t stream) {
    const float* x    = (const float*)d_in[0];
    const float* gn_w = (const float*)d_in[1];
    const float* gn_b = (const float*)d_in[2];
    const float* wq   = (const float*)d_in[3];
    const float* bq   = (const float*)d_in[4];
    const float* wk   = (const float*)d_in[5];
    const float* bk   = (const float*)d_in[6];
    const float* wv   = (const float*)d_in[7];
    const float* bv   = (const float*)d_in[8];
    const float* wo   = (const float*)d_in[9];
    const float* bo   = (const float*)d_in[10];
    float* out = (float*)d_out;

    const size_t WSZ = (size_t)C * C;        // 262144
    const size_t S1  = (size_t)B * C * HW;   // 8,388,608
    u16* wb    = (u16*)d_ws;                 // [q,k,v,o] bf16 weights
    u16* wob   = wb + 3 * WSZ;
    u16* xnT   = wob + WSZ;                  // dead after qkv; oT aliases it
    u16* oT    = xnT;
    u16* qT    = xnT + S1;
    u16* kT    = qT + S1;
    u16* vimg  = kT + S1;
    u16* Opart = vimg + S1;                  // 2*S1 bf16 partials
    float2* ml = (float2*)(Opart + 2 * S1);  // 2*B*HW float2

    hipLaunchKernelGGL(conv_kernel,  dim3(256, 4), dim3(256), 0, stream, wq, wk, wv, wo, wb);
    hipLaunchKernelGGL(gn_kernel,    dim3(B*NG), dim3(256), 0, stream, x, gn_w, gn_b, xnT);
    hipLaunchKernelGGL(qkv_kernel,   dim3(HW/128, 12, B), dim3(256), 0, stream,
                       xnT, wb, bq, bk, bv, qT, kT, vimg);
    hipLaunchKernelGGL(attn_kernel,  dim3(HW/32, B, 2), dim3(256), 0, stream,
                       qT, kT, vimg, Opart, ml);
    hipLaunchKernelGGL(merge_kernel, dim3(B*HW/4), dim3(256), 0, stream, Opart, ml, oT);
    hipLaunchKernelGGL(proj_kernel,  dim3(HW/128, C/128, B), dim3(256), 0, stream, oT, wob, bo, x, out);
}

// Round 10
// 442.700 us; speedup vs baseline: 1.6885x; 1.6885x over previous
//
#include <hip/hip_runtime.h>

#define B 4
#define C 512
#define HW 4096
#define NG 32
#define GSZ 65536   // (C/NG)*HW = 16*4096

typedef unsigned short u16;
typedef unsigned int u32;
typedef __attribute__((ext_vector_type(8))) short short8;
typedef __attribute__((ext_vector_type(4))) float f32x4;

__device__ __forceinline__ float bf2f(u16 u) {
    union { u32 i; float f; } x; x.i = ((u32)u) << 16; return x.f;
}
__device__ __forceinline__ u16 f2bf(float f) {
    union { u32 i; float f; } x; x.f = f;
    u32 r = x.i + 0x7FFF + ((x.i >> 16) & 1);   // round-nearest-even
    return (u16)(r >> 16);
}

// async global->LDS, 16B per lane. LDS dest = wave-uniform base + lane*16.
__device__ __forceinline__ void gld16(const u16* g, u16* l) {
    __builtin_amdgcn_global_load_lds(
        (const __attribute__((address_space(1))) void*)g,
        (__attribute__((address_space(3))) void*)l, 16, 0, 0);
}

// ---------------- Kernel 0: fp32 -> bf16 weight conversion ----------------
__global__ __launch_bounds__(256) void conv_kernel(
        const float* __restrict__ wq, const float* __restrict__ wk,
        const float* __restrict__ wv, const float* __restrict__ wo,
        u16* __restrict__ dst) {
    const int mat = blockIdx.y;
    const float* src = (mat == 0) ? wq : (mat == 1) ? wk : (mat == 2) ? wv : wo;
    const int idx = (blockIdx.x * 256 + threadIdx.x) * 4;
    float4 v = *(const float4*)(src + idx);
    ushort4 r;
    r.x = f2bf(v.x); r.y = f2bf(v.y); r.z = f2bf(v.z); r.w = f2bf(v.w);
    *(ushort4*)(dst + (size_t)mat * (C * C) + idx) = r;
}

// ---------------- Kernel 1: GroupNorm -> bf16 xnT (b, hw, c) ----------------
__global__ __launch_bounds__(256) void gn_kernel(
        const float* __restrict__ x, const float* __restrict__ gamma,
        const float* __restrict__ beta, u16* __restrict__ xnT) {
    const int gl = blockIdx.x;                // b*32 + g
    const int b = gl >> 5, g = gl & 31;
    const size_t base = (size_t)gl * GSZ;
    const int tid = threadIdx.x;
    float s = 0.f, s2 = 0.f;
    for (int i = tid * 4; i < GSZ; i += 1024) {
        float4 v4 = *(const float4*)(x + base + i);
        s  += v4.x + v4.y + v4.z + v4.w;
        s2 += v4.x*v4.x + v4.y*v4.y + v4.z*v4.z + v4.w*v4.w;
    }
    #pragma unroll
    for (int off = 32; off > 0; off >>= 1) {
        s  += __shfl_down(s, off, 64);
        s2 += __shfl_down(s2, off, 64);
    }
    __shared__ float rs[4], rs2[4], bc[2];
    int lane = tid & 63, wid = tid >> 6;
    if (lane == 0) { rs[wid] = s; rs2[wid] = s2; }
    __syncthreads();
    if (tid == 0) {
        float ts  = rs[0] + rs[1] + rs[2] + rs[3];
        float ts2 = rs2[0] + rs2[1] + rs2[2] + rs2[3];
        float mean = ts * (1.f / GSZ);
        float var  = ts2 * (1.f / GSZ) - mean * mean;
        bc[0] = mean; bc[1] = rsqrtf(var + 1e-6f);
    }
    __syncthreads();
    const float mean = bc[0], rstd = bc[1];
    const int c0 = g * 16;
    float gm[16], bt[16];
    #pragma unroll
    for (int c = 0; c < 16; c++) {
        float gg = gamma[c0 + c] * rstd;
        gm[c] = gg;
        bt[c] = beta[c0 + c] - mean * gg;
    }
    for (int i = tid; i < HW; i += 256) {
        u32 pk[8];
        #pragma unroll
        for (int c = 0; c < 16; c += 2) {
            float a0 = x[base + (size_t)c * HW + i] * gm[c] + bt[c];
            float a1 = x[base + (size_t)(c + 1) * HW + i] * gm[c + 1] + bt[c + 1];
            pk[c >> 1] = (u32)f2bf(a0) | ((u32)f2bf(a1) << 16);
        }
        u16* dst = xnT + ((size_t)b * HW + i) * C + c0;
        *(uint4*)dst       = make_uint4(pk[0], pk[1], pk[2], pk[3]);
        *(uint4*)(dst + 8) = make_uint4(pk[4], pk[5], pk[6], pk[7]);
    }
}

// ---------------- Kernel 2: MFMA QKV projection ----------------
// A = xnT (m=i, k=c contig), B = W (n=o, k=c contig) -> D[i,o]
// q/k: store qT/kT (b,hw,c);  v: store vimg swizzled chunks (ushort4 runs)
__global__ __launch_bounds__(256) void qkv_kernel(
        const u16* __restrict__ xnT, const u16* __restrict__ wb,
        const float* __restrict__ bq, const float* __restrict__ bk,
        const float* __restrict__ bv,
        u16* __restrict__ qT, u16* __restrict__ kT, u16* __restrict__ vimg) {
    const int mat = blockIdx.y >> 2;
    const int oT0 = (blockIdx.y & 3) * 128;
    const int iT0 = blockIdx.x * 128;
    const int b = blockIdx.z;
    const u16* Ag = xnT + ((size_t)b * HW + iT0) * C;
    const u16* Bg = wb + (size_t)mat * C * C + (size_t)oT0 * C;
    const float* bias = (mat == 0) ? bq : (mat == 1) ? bk : bv;

    const int tid = threadIdx.x;
    const int w = tid >> 6, lane = tid & 63;
    const int qd = lane >> 4, nn = lane & 15;
    const int wm = w & 1, wn = w >> 1;

    __shared__ __align__(16) u16 As[2][128 * 32];
    __shared__ __align__(16) u16 Bs[2][128 * 32];

    f32x4 acc[4][4];
    #pragma unroll
    for (int mt = 0; mt < 4; mt++)
        #pragma unroll
        for (int nt = 0; nt < 4; nt++) acc[mt][nt] = (f32x4){0.f, 0.f, 0.f, 0.f};

    auto stage = [&](u16* dst, const u16* g, int c0) {
        #pragma unroll
        for (int p = 0; p < 2; p++) {
            int rbase = 32 * w + 16 * p;
            int row = rbase + (lane >> 2);
            gld16(g + (size_t)row * C + c0 + (((lane & 3) ^ ((row >> 1) & 3)) << 3),
                  dst + rbase * 32);
        }
    };

    stage(As[0], Ag, 0);
    stage(Bs[0], Bg, 0);

    for (int kt = 0; kt < 16; kt++) {
        const int cur = kt & 1;
        __syncthreads();
        if (kt < 15) {
            stage(As[cur ^ 1], Ag, (kt + 1) * 32);
            stage(Bs[cur ^ 1], Bg, (kt + 1) * 32);
        }
        short8 af[4], bf[4];
        #pragma unroll
        for (int mt = 0; mt < 4; mt++) {
            int row = 64 * wm + 16 * mt + nn;
            af[mt] = *(const short8*)&As[cur][row * 32 + ((qd ^ ((row >> 1) & 3)) << 3)];
        }
        #pragma unroll
        for (int nt = 0; nt < 4; nt++) {
            int row = 64 * wn + 16 * nt + nn;
            bf[nt] = *(const short8*)&Bs[cur][row * 32 + ((qd ^ ((row >> 1) & 3)) << 3)];
        }
        #pragma unroll
        for (int mt = 0; mt < 4; mt++)
            #pragma unroll
            for (int nt = 0; nt < 4; nt++)
                acc[mt][nt] = __builtin_amdgcn_mfma_f32_16x16x32_bf16(af[mt], bf[nt], acc[mt][nt], 0, 0, 0);
    }

    if (mat < 2) {
        u16* dstT = ((mat == 0) ? qT : kT) + (size_t)b * HW * C;
        #pragma unroll
        for (int nt = 0; nt < 4; nt++) {
            int o = oT0 + 64 * wn + 16 * nt + nn;
            float bb = bias[o];
            #pragma unroll
            for (int mt = 0; mt < 4; mt++) {
                int ib = iT0 + 64 * wm + 16 * mt + qd * 4;
                u16* p = dstT + (size_t)ib * C + o;
                p[0]     = f2bf(acc[mt][nt][0] + bb);
                p[C]     = f2bf(acc[mt][nt][1] + bb);
                p[2 * C] = f2bf(acc[mt][nt][2] + bb);
                p[3 * C] = f2bf(acc[mt][nt][3] + bb);
            }
        }
    } else {
        u16* vb = vimg + (size_t)b * 128 * 16384;
        #pragma unroll
        for (int nt = 0; nt < 4; nt++) {
            int c = oT0 + 64 * wn + 16 * nt + nn;
            float bb = bias[c];
            #pragma unroll
            for (int mt = 0; mt < 4; mt++) {
                int ib = iT0 + 64 * wm + 16 * mt + qd * 4;
                int ch = ib >> 5;
                int j0 = ib & 31;
                ushort4 st;
                st.x = f2bf(acc[mt][nt][0] + bb);
                st.y = f2bf(acc[mt][nt][1] + bb);
                st.z = f2bf(acc[mt][nt][2] + bb);
                st.w = f2bf(acc[mt][nt][3] + bb);
                *(ushort4*)&vb[(size_t)ch * 16384 + c * 32 +
                               (((j0 >> 3) ^ ((c >> 2) & 3)) << 3) + (j0 & 7)] = st;
            }
        }
    }
}

// ---------------- Kernel 3: MFMA flash attention, software-pipelined ----------------
// Block: 32 q-rows, 4 waves, full 4096-j sweep (128 chunks of 32 j).
// Wave w = (rw = w&1 row-half) x (jh = w>>1 j-half) for the 32x32 S tile.
// PV: wave w owns cols [128w, 128w+128) for all 32 rows.
// ONE barrier per chunk: phase t = [V(t) loads + stageK(t+2)] -> S(t+1)+softmax
// -> PV(t) -> alpha-rescale -> barrier. pbuf and mflag parity-double-buffered.
// Epoch bookkeeping exact: p(t+1) at new epoch m, lsum rescaled at add,
// oacc rescaled after PV(t).
__global__ __launch_bounds__(256, 2) void attn_kernel(
        const u16* __restrict__ qT, const u16* __restrict__ kT,
        const u16* __restrict__ vimg, u16* __restrict__ oT) {
    const int b = blockIdx.y;
    const int i0 = blockIdx.x * 32;
    const int tid = threadIdx.x;
    const int w = tid >> 6;
    const int lane = tid & 63;
    const int q = lane >> 4;
    const int n = lane & 15;
    const int rw = w & 1;              // S row-half
    const int jh = w >> 1;             // S j-half within chunk

    __shared__ __align__(16) u16 kbuf[2][32 * 512];   // 64 KB, XOR-chunk swizzle
    __shared__ __align__(16) u16 pbuf[2][32 * 40];    // 5 KB, parity dbuf
    __shared__ __align__(16) float mflag[2][4];       // parity dbuf flags
    __shared__ __align__(16) float lpart[2][32];

    // persistent Q A-fragments: rows i0 + rw*16 + n, k = kk*32 + q*8 .. +7
    short8 qf[16];
    {
        const u16* qrow = qT + ((size_t)b * HW + i0 + rw * 16 + n) * C + q * 8;
        #pragma unroll
        for (int k = 0; k < 16; k++) {
            uint4 u = *(const uint4*)(qrow + k * 32);
            qf[k] = *(const short8*)&u;
        }
    }
    f32x4 oacc[2][8];
    #pragma unroll
    for (int mt = 0; mt < 2; mt++)
        #pragma unroll
        for (int nt = 0; nt < 8; nt++)
            oacc[mt][nt] = (f32x4){0.f, 0.f, 0.f, 0.f};
    float mreg = 0.f;                  // block-uniform epoch max (lockstep)
    float lsum[4] = {0.f, 0.f, 0.f, 0.f};

    const u16* kTb = kT + (size_t)b * HW * C;
    const u16* vTb = vimg + (size_t)b * 128 * 16384;

    // K row j (0..31): phys 16B-chunk l holds logical chunk (l ^ (j&7))
    auto stageK = [&](int gc, int buf) {
        const u16* gk = kTb + (size_t)gc * 32 * C;
        #pragma unroll
        for (int ii = 0; ii < 8; ii++) {
            int j = w * 8 + ii;
            gld16(gk + (size_t)j * C + ((lane ^ (j & 7)) << 3), &kbuf[buf][j * 512]);
        }
    };

    const float scale = 0.04419417382415922f;   // 512^-0.5
    stageK(0, 0);
    stageK(1, 1);
    __syncthreads();   // K(0), K(1) staged

    // ---- prologue: S(0) + softmax(0) -> pbuf[0], mflag[0] ----
    {
        f32x4 sa = {0.f,0.f,0.f,0.f}, sb = {0.f,0.f,0.f,0.f};
        const int sw = n & 7;
        const u16* kb = kbuf[0] + (jh * 16 + n) * 512;
        #pragma unroll
        for (int kk = 0; kk < 8; kk++) {
            short8 bfa = *(const short8*)&kb[(((2 * kk) * 4 + q) ^ sw) << 3];
            short8 bfb = *(const short8*)&kb[(((2 * kk + 1) * 4 + q) ^ sw) << 3];
            sa = __builtin_amdgcn_mfma_f32_16x16x32_bf16(qf[2 * kk], bfa, sa, 0, 0, 0);
            sb = __builtin_amdgcn_mfma_f32_16x16x32_bf16(qf[2 * kk + 1], bfb, sb, 0, 0, 0);
        }
        float sv[4];
        #pragma unroll
        for (int r = 0; r < 4; r++) sv[r] = (sa[r] + sb[r]) * scale;
        float pm = fmaxf(fmaxf(sv[0], sv[1]), fmaxf(sv[2], sv[3]));
        float flagv = -1e30f;
        if (__any(pm > mreg + 1.0f)) {
            float mx = pm;
            mx = fmaxf(mx, __shfl_xor(mx, 1));
            mx = fmaxf(mx, __shfl_xor(mx, 2));
            mx = fmaxf(mx, __shfl_xor(mx, 4));
            mx = fmaxf(mx, __shfl_xor(mx, 8));
            mx = fmaxf(mx, __shfl_xor(mx, 16));
            mx = fmaxf(mx, __shfl_xor(mx, 32));
            flagv = mx;
        }
        if (lane == 0) mflag[0][w] = flagv;
        #pragma unroll
        for (int r = 0; r < 4; r++) {
            float p = __expf(sv[r] - mreg);
            lsum[r] += p;
            pbuf[0][(rw * 16 + q * 4 + r) * 40 + jh * 16 + n] = f2bf(p);
        }
    }
    __syncthreads();   // pbuf[0]/mflag[0] visible

    #pragma unroll 1
    for (int t = 0; t < 128; ++t) {
        const int cur = t & 1;
        // ---- V fragments for chunk t (global, coalesced vimg image) ----
        uint4 vpf[8];
        {
            const u16* gv = vTb + (size_t)t * 16384;
            #pragma unroll
            for (int nt = 0; nt < 8; nt++) {
                int c = w * 128 + nt * 16 + n;
                vpf[nt] = *(const uint4*)&gv[c * 32 + ((q ^ ((c >> 2) & 3)) << 3)];
            }
        }
        if (t < 126) stageK(t + 2, cur);   // kbuf[cur] free (S(t) done last phase)
        // ---- epoch update from S(t) flags (written last phase) ----
        f32x4 fl = *(const f32x4*)mflag[cur];
        float mnew = fmaxf(fmaxf(mreg, fl[0]), fmaxf(fmaxf(fl[1], fl[2]), fl[3]));
        float alpha = 1.f;
        if (mnew > mreg) { alpha = __expf(mreg - mnew); mreg = mnew; }
        if (t < 127) {
            // ---- S(t+1) from kbuf[cur^1] (covers vpf/staging latency) ----
            f32x4 sa = {0.f,0.f,0.f,0.f}, sb = {0.f,0.f,0.f,0.f};
            const int sw = n & 7;
            const u16* kb = kbuf[cur ^ 1] + (jh * 16 + n) * 512;
            #pragma unroll
            for (int kk = 0; kk < 8; kk++) {
                short8 bfa = *(const short8*)&kb[(((2 * kk) * 4 + q) ^ sw) << 3];
                short8 bfb = *(const short8*)&kb[(((2 * kk + 1) * 4 + q) ^ sw) << 3];
                sa = __builtin_amdgcn_mfma_f32_16x16x32_bf16(qf[2 * kk], bfa, sa, 0, 0, 0);
                sb = __builtin_amdgcn_mfma_f32_16x16x32_bf16(qf[2 * kk + 1], bfb, sb, 0, 0, 0);
            }
            float sv[4];
            #pragma unroll
            for (int r = 0; r < 4; r++) sv[r] = (sa[r] + sb[r]) * scale;
            float pm = fmaxf(fmaxf(sv[0], sv[1]), fmaxf(sv[2], sv[3]));
            float flagv = -1e30f;
            if (__any(pm > mreg + 1.0f)) {
                float mx = pm;
                mx = fmaxf(mx, __shfl_xor(mx, 1));
                mx = fmaxf(mx, __shfl_xor(mx, 2));
                mx = fmaxf(mx, __shfl_xor(mx, 4));
                mx = fmaxf(mx, __shfl_xor(mx, 8));
                mx = fmaxf(mx, __shfl_xor(mx, 16));
                mx = fmaxf(mx, __shfl_xor(mx, 32));
                flagv = mx;
            }
            if (lane == 0) mflag[cur ^ 1][w] = flagv;
            #pragma unroll
            for (int r = 0; r < 4; r++) {
                float p = __expf(sv[r] - mreg);
                lsum[r] = lsum[r] * alpha + p;
                pbuf[cur ^ 1][(rw * 16 + q * 4 + r) * 40 + jh * 16 + n] = f2bf(p);
            }
        } else {
            #pragma unroll
            for (int r = 0; r < 4; r++) lsum[r] *= alpha;
        }
        // ---- PV(t) from pbuf[cur] + vpf (adds at chunk t's epoch scale) ----
        short8 pf[2];
        #pragma unroll
        for (int mt = 0; mt < 2; mt++)
            pf[mt] = *(const short8*)&pbuf[cur][(mt * 16 + n) * 40 + q * 8];
        #pragma unroll
        for (int nt = 0; nt < 8; nt++) {
            short8 vf = *(const short8*)&vpf[nt];
            #pragma unroll
            for (int mt = 0; mt < 2; mt++)
                oacc[mt][nt] = __builtin_amdgcn_mfma_f32_16x16x32_bf16(pf[mt], vf, oacc[mt][nt], 0, 0, 0);
        }
        // ---- bring oacc to the new epoch (after chunk t entered at old scale) ----
        if (alpha != 1.f) {
            #pragma unroll
            for (int mt = 0; mt < 2; mt++)
                #pragma unroll
                for (int nt = 0; nt < 8; nt++) {
                    oacc[mt][nt][0] *= alpha; oacc[mt][nt][1] *= alpha;
                    oacc[mt][nt][2] *= alpha; oacc[mt][nt][3] *= alpha;
                }
        }
        __syncthreads();   // drains stageK(t+2); pbuf/mflag(t+1) visible
    }
    // ---- epilogue: per-(row,jh) partial l -> LDS; write normalized oT ----
    #pragma unroll
    for (int r = 0; r < 4; r++) {
        float l = lsum[r];
        l += __shfl_xor(l, 1);
        l += __shfl_xor(l, 2);
        l += __shfl_xor(l, 4);
        l += __shfl_xor(l, 8);
        if (n == 0) lpart[jh][rw * 16 + q * 4 + r] = l;
    }
    __syncthreads();
    #pragma unroll
    for (int mt = 0; mt < 2; mt++) {
        float inv[4];
        #pragma unroll
        for (int r = 0; r < 4; r++) {
            int row = mt * 16 + q * 4 + r;
            inv[r] = 1.f / (lpart[0][row] + lpart[1][row]);
        }
        #pragma unroll
        for (int nt = 0; nt < 8; nt++) {
            int cc = w * 128 + nt * 16 + n;
            size_t base = ((size_t)b * HW + i0 + mt * 16 + q * 4) * C + cc;
            oT[base        ] = f2bf(oacc[mt][nt][0] * inv[0]);
            oT[base +   C  ] = f2bf(oacc[mt][nt][1] * inv[1]);
            oT[base + 2 * C] = f2bf(oacc[mt][nt][2] * inv[2]);
            oT[base + 3 * C] = f2bf(oacc[mt][nt][3] * inv[3]);
        }
    }
}

// ---------------- Kernel 4: MFMA output projection + bias + residual ----------------
// A = wo (m=o, k=c), B = oT (n=i, k=c) -> D[o,i] (c-major output)
__global__ __launch_bounds__(256) void proj_kernel(
        const u16* __restrict__ oT, const u16* __restrict__ wob,
        const float* __restrict__ bo, const float* __restrict__ x,
        float* __restrict__ out) {
    const int o0 = blockIdx.y * 128;
    const int i0t = blockIdx.x * 128;
    const int b = blockIdx.z;
    const u16* Ag = wob + (size_t)o0 * C;
    const u16* Bg = oT + ((size_t)b * HW + i0t) * C;

    const int tid = threadIdx.x;
    const int w = tid >> 6, lane = tid & 63;
    const int qd = lane >> 4, nn = lane & 15;
    const int wm = w & 1, wn = w >> 1;

    __shared__ __align__(16) u16 As[2][128 * 32];
    __shared__ __align__(16) u16 Bs[2][128 * 32];

    f32x4 acc[4][4];
    #pragma unroll
    for (int mt = 0; mt < 4; mt++)
        #pragma unroll
        for (int nt = 0; nt < 4; nt++) acc[mt][nt] = (f32x4){0.f, 0.f, 0.f, 0.f};

    auto stage = [&](u16* dst, const u16* g, int c0) {
        #pragma unroll
        for (int p = 0; p < 2; p++) {
            int rbase = 32 * w + 16 * p;
            int row = rbase + (lane >> 2);
            gld16(g + (size_t)row * C + c0 + (((lane & 3) ^ ((row >> 1) & 3)) << 3),
                  dst + rbase * 32);
        }
    };

    stage(As[0], Ag, 0);
    stage(Bs[0], Bg, 0);

    for (int kt = 0; kt < 16; kt++) {
        const int cur = kt & 1;
        __syncthreads();
        if (kt < 15) {
            stage(As[cur ^ 1], Ag, (kt + 1) * 32);
            stage(Bs[cur ^ 1], Bg, (kt + 1) * 32);
        }
        short8 af[4], bf[4];
        #pragma unroll
        for (int mt = 0; mt < 4; mt++) {
            int row = 64 * wm + 16 * mt + nn;
            af[mt] = *(const short8*)&As[cur][row * 32 + ((qd ^ ((row >> 1) & 3)) << 3)];
        }
        #pragma unroll
        for (int nt = 0; nt < 4; nt++) {
            int row = 64 * wn + 16 * nt + nn;
            bf[nt] = *(const short8*)&Bs[cur][row * 32 + ((qd ^ ((row >> 1) & 3)) << 3)];
        }
        #pragma unroll
        for (int mt = 0; mt < 4; mt++)
            #pragma unroll
            for (int nt = 0; nt < 4; nt++)
                acc[mt][nt] = __builtin_amdgcn_mfma_f32_16x16x32_bf16(af[mt], bf[nt], acc[mt][nt], 0, 0, 0);
    }

    #pragma unroll
    for (int mt = 0; mt < 4; mt++) {
        #pragma unroll
        for (int r = 0; r < 4; r++) {
            int o = o0 + 64 * wm + 16 * mt + qd * 4 + r;
            float bb = bo[o];
            #pragma unroll
            for (int nt = 0; nt < 4; nt++) {
                int i = i0t + 64 * wn + 16 * nt + nn;
                size_t idx = ((size_t)b * C + o) * HW + i;
                out[idx] = acc[mt][nt][r] + bb + x[idx];
            }
        }
    }
}

extern "C" void kernel_launch(void* const* d_in, const int* in_sizes, int n_in,
                              void* d_out, int out_size, void* d_ws, size_t ws_size,
                              hipStream_t stream) {
    const float* x    = (const float*)d_in[0];
    const float* gn_w = (const float*)d_in[1];
    const float* gn_b = (const float*)d_in[2];
    const float* wq   = (const float*)d_in[3];
    const float* bq   = (const float*)d_in[4];
    const float* wk   = (const float*)d_in[5];
    const float* bk   = (const float*)d_in[6];
    const float* wv   = (const float*)d_in[7];
    const float* bv   = (const float*)d_in[8];
    const float* wo   = (const float*)d_in[9];
    const float* bo   = (const float*)d_in[10];
    float* out = (float*)d_out;

    const size_t WSZ = (size_t)C * C;        // 262144
    const size_t S1  = (size_t)B * C * HW;   // 8,388,608
    u16* wb    = (u16*)d_ws;                 // [q,k,v,o] bf16 weights
    u16* wob   = wb + 3 * WSZ;
    u16* xnT   = wob + WSZ;
    u16* qT    = xnT + S1;
    u16* kT    = qT + S1;
    u16* vimg  = kT + S1;
    u16* oT    = vimg + S1;

    hipLaunchKernelGGL(conv_kernel,  dim3(256, 4), dim3(256), 0, stream, wq, wk, wv, wo, wb);
    hipLaunchKernelGGL(gn_kernel,    dim3(B*NG), dim3(256), 0, stream, x, gn_w, gn_b, xnT);
    hipLaunchKernelGGL(qkv_kernel,   dim3(HW/128, 12, B), dim3(256), 0, stream,
                       xnT, wb, bq, bk, bv, qT, kT, vimg);
    hipLaunchKernelGGL(attn_kernel,  dim3(HW/32, B), dim3(256), 0, stream,
                       qT, kT, vimg, oT);
    hipLaunchKernelGGL(proj_kernel,  dim3(HW/128, C/128, B), dim3(256), 0, stream, oT, wob, bo, x, out);
}